// Round 2
// baseline (1713.031 us; speedup 1.0000x reference)
//
#include <hip/hip_runtime.h>
#include <hip/hip_bf16.h>
#include <math.h>

#define EPSC 1e-5f

constexpr int Bn = 16, Cn = 96, Hn = 112, Wn = 112, HWn = Hn * Wn; // 12544
constexpr int D4n = 384;
constexpr int NT  = 64;            // spatial tile
constexpr int TPI = HWn / NT;      // 196 tiles per image plane
constexpr int XST = NT + 4;        // 68 padded stride

union U4 { ushort4 u; __hip_bfloat16 h[4]; };

__device__ __forceinline__ float gelu_f(float x) {
    return 0.5f * x * (1.0f + erff(x * 0.70710678118654752f));
}

// ---------------- BN folding: y = acc*A + B ----------------
// P layout: A1[0:96] B1[96:192] Ag[192:384] Bg[384:576] A2[576:672] B2[672:768]
__global__ __launch_bounds__(256) void params_kernel(
    const float* __restrict__ b1, const float* __restrict__ g1, const float* __restrict__ be1,
    const float* __restrict__ m1, const float* __restrict__ v1,
    const float* __restrict__ bg, const float* __restrict__ gg, const float* __restrict__ beg,
    const float* __restrict__ mg, const float* __restrict__ vg,
    const float* __restrict__ b2, const float* __restrict__ g2, const float* __restrict__ be2,
    const float* __restrict__ m2, const float* __restrict__ v2,
    float* __restrict__ P)
{
    int t = threadIdx.x;
    if (t < 96) {
        float s = g1[t] * rsqrtf(v1[t] + EPSC);
        P[t]       = s;
        P[96 + t]  = (b1[t] - m1[t]) * s + be1[t];
        float s2 = g2[t] * rsqrtf(v2[t] + EPSC);
        P[576 + t] = s2;
        P[672 + t] = (b2[t] - m2[t]) * s2 + be2[t];
    }
    if (t < 192) {
        float s = gg[t] * rsqrtf(vg[t] + EPSC);
        P[192 + t] = s;
        P[384 + t] = (bg[t] - mg[t]) * s + beg[t];
    }
}

// ---------------- fc1 + BN -> h (bf16) ----------------
__global__ __launch_bounds__(256) void fc1_kernel(
    const float* __restrict__ Xin, const float* __restrict__ Wt,
    const float* __restrict__ Pr, __hip_bfloat16* __restrict__ Hout)
{
    __shared__ float Xs[96 * XST];   // 26.1 KB
    __shared__ float Wc[64 * XST];   // 17.4 KB

    const int bid = blockIdx.x;
    const int b   = bid / TPI;
    const int hw0 = (bid - b * TPI) * NT;
    const int t   = threadIdx.x;
    const int l16 = t & 15;
    const int grp = t >> 4;

    #pragma unroll
    for (int p = 0; p < 6; ++p) {
        int c = grp + 16 * p;
        float4 v = *(const float4*)(Xin + ((size_t)(b * Cn + c)) * HWn + hw0 + 4 * l16);
        *(float4*)(&Xs[c * XST + 4 * l16]) = v;
    }

    for (int oc = 0; oc < 2; ++oc) {
        const int osz = (oc == 0) ? 64 : 32;
        float acc[4][4] = {};
        for (int k0 = 0; k0 < 96; k0 += 64) {
            const int kc = (96 - k0 < 64) ? (96 - k0) : 64;
            __syncthreads();
            for (int o = grp; o < osz; o += 16) {
                if (4 * l16 < kc) {
                    float4 wv = *(const float4*)(Wt + (size_t)(oc * 64 + o) * 96 + k0 + 4 * l16);
                    Wc[(4 * l16 + 0) * XST + o] = wv.x;
                    Wc[(4 * l16 + 1) * XST + o] = wv.y;
                    Wc[(4 * l16 + 2) * XST + o] = wv.z;
                    Wc[(4 * l16 + 3) * XST + o] = wv.w;
                }
            }
            __syncthreads();
            if (4 * grp < osz) {
                #pragma unroll 4
                for (int k = 0; k < kc; ++k) {
                    float4 x4 = *(const float4*)(&Xs[(k0 + k) * XST + 4 * l16]);
                    float4 w4 = *(const float4*)(&Wc[k * XST + 4 * grp]);
                    float xv[4] = {x4.x, x4.y, x4.z, x4.w};
                    float wv[4] = {w4.x, w4.y, w4.z, w4.w};
                    #pragma unroll
                    for (int u = 0; u < 4; ++u)
                        #pragma unroll
                        for (int v = 0; v < 4; ++v)
                            acc[u][v] += wv[u] * xv[v];
                }
            }
        }
        if (4 * grp < osz) {
            #pragma unroll
            for (int u = 0; u < 4; ++u) {
                int o = oc * 64 + 4 * grp + u;
                float a = Pr[o], sh = Pr[96 + o];
                U4 pk;
                pk.h[0] = __float2bfloat16(acc[u][0] * a + sh);
                pk.h[1] = __float2bfloat16(acc[u][1] * a + sh);
                pk.h[2] = __float2bfloat16(acc[u][2] * a + sh);
                pk.h[3] = __float2bfloat16(acc[u][3] * a + sh);
                *(ushort4*)(Hout + ((size_t)(b * Cn + o)) * HWn + hw0 + 4 * l16) = pk.u;
            }
        }
    }
}

// ---------------- parity mins over each (b,c) plane ----------------
__global__ __launch_bounds__(256) void mins_kernel(
    const __hip_bfloat16* __restrict__ Hc, float* __restrict__ cmin, float* __restrict__ rmin)
{
    __shared__ float pl[112 * 113];
    const int bc = blockIdx.x;
    const __hip_bfloat16* base = Hc + (size_t)bc * HWn;
    const int t = threadIdx.x;
    #pragma unroll
    for (int p = 0; p < 49; ++p) {
        int idx = t + 256 * p;
        int i = idx / Wn, j = idx - i * Wn;
        pl[i * 113 + j] = __bfloat162float(base[idx]);
    }
    __syncthreads();
    if (t < 224) {
        int i = t % 112, p = t / 112;
        float m = 1e30f;
        #pragma unroll 8
        for (int n = 0; n < 56; ++n) m = fminf(m, pl[i * 113 + p + 2 * n]);
        rmin[((size_t)bc * Hn + i) * 2 + p] = m;

        int j = i;
        float m2 = 1e30f;
        #pragma unroll 8
        for (int n = 0; n < 56; ++n) m2 = fminf(m2, pl[(p + 2 * n) * 113 + j]);
        cmin[((size_t)bc * 2 + p) * Wn + j] = m2;
    }
}

// ---------------- fused grapher: cat -> fc_g+BN+GELU -> fc2+BN+residual -> r (d_out) ----------------
__global__ __launch_bounds__(256) void grapher_kernel(
    const __hip_bfloat16* __restrict__ Hbf,
    const float* __restrict__ Wg, const float* __restrict__ W2,
    const float* __restrict__ Pr,
    const float* __restrict__ cmin, const float* __restrict__ rmin,
    const float* __restrict__ Xres, float* __restrict__ Out)
{
    __shared__ float Xs[192 * XST];  // 52.2 KB cat tile
    __shared__ float Gs[192 * XST];  // 52.2 KB g tile
    __shared__ float Wc[64 * XST];   // 17.4 KB

    const int bid = blockIdx.x;
    const int b   = bid / TPI;
    const int hw0 = (bid - b * TPI) * NT;
    const int t   = threadIdx.x;
    const int l16 = t & 15;
    const int grp = t >> 4;

    // ---- stage cat tile: channels 0..95 = h, 96..191 = xj ----
    #pragma unroll
    for (int p = 0; p < 12; ++p) {
        int c = grp + 16 * p;
        int cc = (c < Cn) ? c : (c - Cn);
        U4 hv;
        hv.u = *(const ushort4*)(Hbf + ((size_t)(b * Cn + cc)) * HWn + hw0 + 4 * l16);
        float r[4];
        #pragma unroll
        for (int e = 0; e < 4; ++e) r[e] = __bfloat162float(hv.h[e]);
        if (c >= Cn) {
            #pragma unroll
            for (int e = 0; e < 4; ++e) {
                int pos = hw0 + 4 * l16 + e;
                int i = pos / Wn, j = pos - i * Wn;
                float cm = cmin[((size_t)(b * Cn + cc) * 2 + (i & 1)) * Wn + j];
                float rm = rmin[((size_t)(b * Cn + cc) * Hn + i) * 2 + (j & 1)];
                r[e] = fmaxf(r[e] - cm, r[e] - rm);   // mins include self => >= 0
            }
        }
        *(float4*)(&Xs[c * XST + 4 * l16]) = make_float4(r[0], r[1], r[2], r[3]);
    }

    // ---- GEMM-G: g = gelu(BN(Wg * cat)), M=192, K=192 -> Gs ----
    for (int oc = 0; oc < 3; ++oc) {
        float acc[4][4] = {};
        for (int k0 = 0; k0 < 192; k0 += 64) {
            __syncthreads();
            for (int o = grp; o < 64; o += 16) {
                float4 wv = *(const float4*)(Wg + (size_t)(oc * 64 + o) * 192 + k0 + 4 * l16);
                Wc[(4 * l16 + 0) * XST + o] = wv.x;
                Wc[(4 * l16 + 1) * XST + o] = wv.y;
                Wc[(4 * l16 + 2) * XST + o] = wv.z;
                Wc[(4 * l16 + 3) * XST + o] = wv.w;
            }
            __syncthreads();
            #pragma unroll 4
            for (int k = 0; k < 64; ++k) {
                float4 x4 = *(const float4*)(&Xs[(k0 + k) * XST + 4 * l16]);
                float4 w4 = *(const float4*)(&Wc[k * XST + 4 * grp]);
                float xv[4] = {x4.x, x4.y, x4.z, x4.w};
                float wv[4] = {w4.x, w4.y, w4.z, w4.w};
                #pragma unroll
                for (int u = 0; u < 4; ++u)
                    #pragma unroll
                    for (int v = 0; v < 4; ++v)
                        acc[u][v] += wv[u] * xv[v];
            }
        }
        #pragma unroll
        for (int u = 0; u < 4; ++u) {
            int o = oc * 64 + 4 * grp + u;
            float a = Pr[192 + o], sh = Pr[384 + o];
            Gs[o * XST + 4 * l16 + 0] = gelu_f(acc[u][0] * a + sh);
            Gs[o * XST + 4 * l16 + 1] = gelu_f(acc[u][1] * a + sh);
            Gs[o * XST + 4 * l16 + 2] = gelu_f(acc[u][2] * a + sh);
            Gs[o * XST + 4 * l16 + 3] = gelu_f(acc[u][3] * a + sh);
        }
    }

    // ---- GEMM-2: r = BN(W2 * g) + x, M=96, K=192 -> Out (d_out) ----
    for (int oc = 0; oc < 2; ++oc) {
        const int osz = (oc == 0) ? 64 : 32;
        float acc[4][4] = {};
        for (int k0 = 0; k0 < 192; k0 += 64) {
            __syncthreads();
            for (int o = grp; o < osz; o += 16) {
                float4 wv = *(const float4*)(W2 + (size_t)(oc * 64 + o) * 192 + k0 + 4 * l16);
                Wc[(4 * l16 + 0) * XST + o] = wv.x;
                Wc[(4 * l16 + 1) * XST + o] = wv.y;
                Wc[(4 * l16 + 2) * XST + o] = wv.z;
                Wc[(4 * l16 + 3) * XST + o] = wv.w;
            }
            __syncthreads();
            if (4 * grp < osz) {
                #pragma unroll 4
                for (int k = 0; k < 64; ++k) {
                    float4 x4 = *(const float4*)(&Gs[(k0 + k) * XST + 4 * l16]);
                    float4 w4 = *(const float4*)(&Wc[k * XST + 4 * grp]);
                    float xv[4] = {x4.x, x4.y, x4.z, x4.w};
                    float wv[4] = {w4.x, w4.y, w4.z, w4.w};
                    #pragma unroll
                    for (int u = 0; u < 4; ++u)
                        #pragma unroll
                        for (int v = 0; v < 4; ++v)
                            acc[u][v] += wv[u] * xv[v];
                }
            }
        }
        if (4 * grp < osz) {
            #pragma unroll
            for (int u = 0; u < 4; ++u) {
                int o = oc * 64 + 4 * grp + u;
                float a = Pr[576 + o], sh = Pr[672 + o];
                float4 rv = *(const float4*)(Xres + ((size_t)(b * Cn + o)) * HWn + hw0 + 4 * l16);
                float4 y;
                y.x = acc[u][0] * a + sh + rv.x;
                y.y = acc[u][1] * a + sh + rv.y;
                y.z = acc[u][2] * a + sh + rv.z;
                y.w = acc[u][3] * a + sh + rv.w;
                *(float4*)(Out + ((size_t)(b * Cn + o)) * HWn + hw0 + 4 * l16) = y;
            }
        }
    }
}

// ---------------- fused FFN, IN-PLACE on d_out ----------------
__global__ __launch_bounds__(256) void ffn_kernel(
    const float* __restrict__ Rin,
    const float* __restrict__ Wf1, const float* __restrict__ bf1,
    const float* __restrict__ Wf2, const float* __restrict__ bf2,
    float* __restrict__ Out)
{
    __shared__ float Rl[96 * XST];      // 26.1 KB
    __shared__ float Mid[D4n * XST];    // 104.4 KB
    __shared__ float Wc[64 * XST];      // 17.4 KB

    const int bid = blockIdx.x;
    const int b   = bid / TPI;
    const int hw0 = (bid - b * TPI) * NT;
    const int t   = threadIdx.x;
    const int l16 = t & 15;
    const int grp = t >> 4;

    #pragma unroll
    for (int p = 0; p < 6; ++p) {
        int c = grp + 16 * p;
        float4 v = *(const float4*)(Rin + ((size_t)(b * 96 + c)) * HWn + hw0 + 4 * l16);
        *(float4*)(&Rl[c * XST + 4 * l16]) = v;
    }

    // GEMM1: Mid = gelu(Wf1 * r + bf1), M=384, K=96
    for (int oc = 0; oc < 6; ++oc) {
        float acc[4][4] = {};
        for (int k0 = 0; k0 < 96; k0 += 64) {
            const int kc = (96 - k0 < 64) ? (96 - k0) : 64;
            __syncthreads();
            for (int o = grp; o < 64; o += 16) {
                if (4 * l16 < kc) {
                    float4 wv = *(const float4*)(Wf1 + (size_t)(oc * 64 + o) * 96 + k0 + 4 * l16);
                    Wc[(4 * l16 + 0) * XST + o] = wv.x;
                    Wc[(4 * l16 + 1) * XST + o] = wv.y;
                    Wc[(4 * l16 + 2) * XST + o] = wv.z;
                    Wc[(4 * l16 + 3) * XST + o] = wv.w;
                }
            }
            __syncthreads();
            #pragma unroll 4
            for (int k = 0; k < kc; ++k) {
                float4 x4 = *(const float4*)(&Rl[(k0 + k) * XST + 4 * l16]);
                float4 w4 = *(const float4*)(&Wc[k * XST + 4 * grp]);
                float xv[4] = {x4.x, x4.y, x4.z, x4.w};
                float wv[4] = {w4.x, w4.y, w4.z, w4.w};
                #pragma unroll
                for (int u = 0; u < 4; ++u)
                    #pragma unroll
                    for (int v = 0; v < 4; ++v)
                        acc[u][v] += wv[u] * xv[v];
            }
        }
        #pragma unroll
        for (int u = 0; u < 4; ++u) {
            int o = oc * 64 + 4 * grp + u;
            float bb = bf1[o];
            Mid[o * XST + 4 * l16 + 0] = gelu_f(acc[u][0] + bb);
            Mid[o * XST + 4 * l16 + 1] = gelu_f(acc[u][1] + bb);
            Mid[o * XST + 4 * l16 + 2] = gelu_f(acc[u][2] + bb);
            Mid[o * XST + 4 * l16 + 3] = gelu_f(acc[u][3] + bb);
        }
    }

    // GEMM2: Out = Wf2 * Mid + bf2, M=96, K=384
    for (int oc = 0; oc < 2; ++oc) {
        const int osz = (oc == 0) ? 64 : 32;
        float acc[4][4] = {};
        for (int k0 = 0; k0 < 384; k0 += 64) {
            __syncthreads();
            for (int o = grp; o < osz; o += 16) {
                float4 wv = *(const float4*)(Wf2 + (size_t)(oc * 64 + o) * 384 + k0 + 4 * l16);
                Wc[(4 * l16 + 0) * XST + o] = wv.x;
                Wc[(4 * l16 + 1) * XST + o] = wv.y;
                Wc[(4 * l16 + 2) * XST + o] = wv.z;
                Wc[(4 * l16 + 3) * XST + o] = wv.w;
            }
            __syncthreads();
            if (4 * grp < osz) {
                #pragma unroll 4
                for (int k = 0; k < 64; ++k) {
                    float4 x4 = *(const float4*)(&Mid[(k0 + k) * XST + 4 * l16]);
                    float4 w4 = *(const float4*)(&Wc[k * XST + 4 * grp]);
                    float xv[4] = {x4.x, x4.y, x4.z, x4.w};
                    float wv[4] = {w4.x, w4.y, w4.z, w4.w};
                    #pragma unroll
                    for (int u = 0; u < 4; ++u)
                        #pragma unroll
                        for (int v = 0; v < 4; ++v)
                            acc[u][v] += wv[u] * xv[v];
                }
            }
        }
        if (4 * grp < osz) {
            #pragma unroll
            for (int u = 0; u < 4; ++u) {
                int o = oc * 64 + 4 * grp + u;
                float bb = bf2[o];
                float4 y;
                y.x = acc[u][0] + bb;
                y.y = acc[u][1] + bb;
                y.z = acc[u][2] + bb;
                y.w = acc[u][3] + bb;
                *(float4*)(Out + ((size_t)(b * 96 + o)) * HWn + hw0 + 4 * l16) = y;
            }
        }
    }
}

extern "C" void kernel_launch(void* const* d_in, const int* in_sizes, int n_in,
                              void* d_out, int out_size, void* d_ws, size_t ws_size,
                              hipStream_t stream) {
    (void)in_sizes; (void)n_in; (void)out_size; (void)ws_size;
    const float* x   = (const float*)d_in[0];
    const float* w1  = (const float*)d_in[1];
    const float* b1  = (const float*)d_in[2];
    const float* g1  = (const float*)d_in[3];
    const float* be1 = (const float*)d_in[4];
    const float* m1  = (const float*)d_in[5];
    const float* v1  = (const float*)d_in[6];
    const float* wg  = (const float*)d_in[7];
    const float* bg  = (const float*)d_in[8];
    const float* gg  = (const float*)d_in[9];
    const float* beg = (const float*)d_in[10];
    const float* mg  = (const float*)d_in[11];
    const float* vg  = (const float*)d_in[12];
    const float* w2  = (const float*)d_in[13];
    const float* b2  = (const float*)d_in[14];
    const float* g2  = (const float*)d_in[15];
    const float* be2 = (const float*)d_in[16];
    const float* m2  = (const float*)d_in[17];
    const float* v2  = (const float*)d_in[18];
    const float* wf1 = (const float*)d_in[19];
    const float* bf1 = (const float*)d_in[20];
    const float* wf2 = (const float*)d_in[21];
    const float* bf2 = (const float*)d_in[22];
    float* out = (float*)d_out;

    // ---- workspace layout (bytes): h(bf16) | cmin | rmin | prm  ≈ 41.3 MB ----
    char* base = (char*)d_ws;
    const size_t H_BYTES = (size_t)Bn * Cn * HWn * sizeof(__hip_bfloat16);   // 38,535,168
    const size_t MIN_BYTES = (size_t)Bn * Cn * 2 * Wn * sizeof(float);       // 1,376,256
    __hip_bfloat16* hbf = (__hip_bfloat16*)base;
    float* cmin = (float*)(base + H_BYTES);
    float* rmin = (float*)(base + H_BYTES + MIN_BYTES);
    float* prm  = (float*)(base + H_BYTES + 2 * MIN_BYTES);

    params_kernel<<<dim3(1), dim3(256), 0, stream>>>(
        b1, g1, be1, m1, v1, bg, gg, beg, mg, vg, b2, g2, be2, m2, v2, prm);

    dim3 grid(Bn * TPI);  // 3136
    dim3 blk(256);

    // fc1 + BN -> h (bf16)
    fc1_kernel<<<grid, blk, 0, stream>>>(x, w1, prm, hbf);

    // parity mins of h
    mins_kernel<<<dim3(Bn * Cn), blk, 0, stream>>>(hbf, cmin, rmin);

    // fused: cat -> fc_g+BN+GELU -> fc2+BN+residual -> r (into d_out)
    grapher_kernel<<<grid, blk, 0, stream>>>(hbf, wg, w2, prm, cmin, rmin, x, out);

    // fused FFN in-place on d_out
    ffn_kernel<<<grid, blk, 0, stream>>>(out, wf1, bf1, wf2, bf2, out);
}

// Round 3
// 309.574 us; speedup vs baseline: 5.5335x; 5.5335x over previous
//
#include <hip/hip_runtime.h>
#include <hip/hip_bf16.h>
#include <math.h>

#define EPSC 1e-5f

typedef __attribute__((ext_vector_type(8))) short bf16x8;
typedef __attribute__((ext_vector_type(4))) float f32x4;
typedef __attribute__((ext_vector_type(8))) unsigned short u16x8;

constexpr int Bn = 16, Cn = 96, Hn = 112, Wn = 112, HWn = Hn * Wn; // 12544
constexpr int NT = 64, TPI = HWn / NT;                             // 196

#define MFMA16(a, b, c) __builtin_amdgcn_mfma_f32_16x16x32_bf16((a), (b), (c), 0, 0, 0)

__device__ __forceinline__ ushort f2bf(float f) {
    __hip_bfloat16 h = __float2bfloat16(f);
    return __builtin_bit_cast(ushort, h);
}
__device__ __forceinline__ float bf2f(ushort u) {
    return __builtin_bit_cast(float, (unsigned)u << 16);
}
__device__ __forceinline__ float gelu_f(float x) {
    return 0.5f * x * (1.0f + erff(x * 0.70710678118654752f));
}

// ---------------- BN folding ----------------
// prm: A1[0:96] B1[96:192] Ag[192:384] Bg[384:576] A2[576:672] B2[672:768]
__global__ __launch_bounds__(256) void params_kernel(
    const float* __restrict__ b1, const float* __restrict__ g1, const float* __restrict__ be1,
    const float* __restrict__ m1, const float* __restrict__ v1,
    const float* __restrict__ bg, const float* __restrict__ gg, const float* __restrict__ beg,
    const float* __restrict__ mg, const float* __restrict__ vg,
    const float* __restrict__ b2, const float* __restrict__ g2, const float* __restrict__ be2,
    const float* __restrict__ m2, const float* __restrict__ v2,
    float* __restrict__ P)
{
    int t = threadIdx.x;
    if (t < 96) {
        float s = g1[t] * rsqrtf(v1[t] + EPSC);
        P[t]       = s;
        P[96 + t]  = (b1[t] - m1[t]) * s + be1[t];
        float s2 = g2[t] * rsqrtf(v2[t] + EPSC);
        P[576 + t] = s2;
        P[672 + t] = (b2[t] - m2[t]) * s2 + be2[t];
    }
    if (t < 192) {
        float s = gg[t] * rsqrtf(vg[t] + EPSC);
        P[192 + t] = s;
        P[384 + t] = (bg[t] - mg[t]) * s + beg[t];
    }
}

// ---------------- weight pack: fragment order [mt][kc][lane][8], bf16 ----------------
// element (lane,e) = W[mt*16 + lane%16][kc*32 + (lane>>4)*8 + e]
__global__ __launch_bounds__(256) void pack_kernel(
    const float* __restrict__ w1, const float* __restrict__ wg, const float* __restrict__ w2,
    const float* __restrict__ wf1, const float* __restrict__ wf2,
    ushort* __restrict__ dst)
{
    int idx = blockIdx.x * 256 + threadIdx.x;
    if (idx >= 138240) return;
    const float* src; int K, off;
    if      (idx <   9216) { src = w1;  K =  96; off = 0;      }
    else if (idx <  46080) { src = wg;  K = 192; off = 9216;   }
    else if (idx <  64512) { src = w2;  K = 192; off = 46080;  }
    else if (idx < 101376) { src = wf1; K =  96; off = 64512;  }
    else                   { src = wf2; K = 384; off = 101376; }
    int r = idx - off;
    int e = r & 7, lane = (r >> 3) & 63, tile = r >> 9;
    int KC = K / 32;
    int kc = tile % KC, mt = tile / KC;
    int row = mt * 16 + (lane & 15);
    int col = kc * 32 + (lane >> 4) * 8 + e;
    dst[idx] = f2bf(src[(size_t)row * K + col]);
}

// ---------------- parity mins ----------------
// rmin2[b][i][p][c] = min over cols j (j&1==p) of h[b,i,j,c]
// cmin2[b][j][p][c] = min over rows i (i&1==p) of h[b,i,j,c]
__global__ __launch_bounds__(256) void mins_kernel(
    const ushort* __restrict__ h, float* __restrict__ rmin2, float* __restrict__ cmin2)
{
    __shared__ __align__(16) ushort sl[112 * 96];
    int bid = blockIdx.x;            // Bn * 2 * 112
    int b = bid / 224, rem = bid % 224, mode = rem / 112, line = rem % 112;
    int t = threadIdx.x;
    if (mode == 0) {                 // row slab [j][c], contiguous
        const ushort* base = h + ((size_t)b * HWn + line * Wn) * Cn;
        for (int v = t; v < 1344; v += 256)
            *(u16x8*)&sl[v * 8] = *(const u16x8*)&base[v * 8];
    } else {                         // col slab [i][c]
        for (int v = t; v < 1344; v += 256) {
            int i = v / 12, g = v % 12;
            *(u16x8*)&sl[(i * 12 + g) * 8] =
                *(const u16x8*)&h[((size_t)b * HWn + i * Wn + line) * Cn + g * 8];
        }
    }
    __syncthreads();
    if (t < 192) {
        int c = t % 96, p = t / 96;
        float m = 1e30f;
        #pragma unroll 8
        for (int n = 0; n < 56; ++n) m = fminf(m, bf2f(sl[(p + 2 * n) * 96 + c]));
        float* dst = (mode == 0) ? rmin2 : cmin2;
        dst[(((size_t)b * 112 + line) * 2 + p) * 96 + c] = m;
    }
}

// ---------------- fc1: h = BN(W1 x) -> bf16 [b][hw][96] ----------------
__global__ __launch_bounds__(256) void fc1_kernel(
    const float* __restrict__ X, const ushort* __restrict__ w1p,
    const float* __restrict__ prm, ushort* __restrict__ hbuf)
{
    __shared__ __align__(16) ushort Hs[64 * 104];
    int bid = blockIdx.x, b = bid / TPI, hw0 = (bid % TPI) * NT;
    int t = threadIdx.x, lane = t & 63, wave = t >> 6;
    int wm = wave >> 1, wn = wave & 1, q = lane >> 4, sl = lane & 15;

    // B-frags straight from global fp32 (coalesced across lanes)
    bf16x8 bfr[3][2];
    #pragma unroll
    for (int kc = 0; kc < 3; ++kc)
        #pragma unroll
        for (int nc = 0; nc < 2; ++nc) {
            int s = hw0 + wn * 32 + nc * 16 + sl;
            union { bf16x8 v; ushort u[8]; } f;
            #pragma unroll
            for (int e = 0; e < 8; ++e) {
                int c = kc * 32 + q * 8 + e;
                f.u[e] = f2bf(X[((size_t)b * Cn + c) * HWn + s]);
            }
            bfr[kc][nc] = f.v;
        }
    f32x4 acc[3][2] = {};
    #pragma unroll
    for (int kc = 0; kc < 3; ++kc)
        #pragma unroll
        for (int m = 0; m < 3; ++m) {
            bf16x8 af = *(const bf16x8*)&w1p[(((wm * 3 + m) * 3 + kc) * 64 + lane) * 8];
            acc[m][0] = MFMA16(af, bfr[kc][0], acc[m][0]);
            acc[m][1] = MFMA16(af, bfr[kc][1], acc[m][1]);
        }
    #pragma unroll
    for (int m = 0; m < 3; ++m) {
        int o0 = (wm * 3 + m) * 16 + q * 4;
        f32x4 a4 = *(const f32x4*)&prm[o0];
        f32x4 s4 = *(const f32x4*)&prm[96 + o0];
        #pragma unroll
        for (int nc = 0; nc < 2; ++nc) {
            int srow = wn * 32 + nc * 16 + sl;
            ushort4 pk;
            pk.x = f2bf(acc[m][nc][0] * a4[0] + s4[0]);
            pk.y = f2bf(acc[m][nc][1] * a4[1] + s4[1]);
            pk.z = f2bf(acc[m][nc][2] * a4[2] + s4[2]);
            pk.w = f2bf(acc[m][nc][3] * a4[3] + s4[3]);
            *(ushort4*)&Hs[srow * 104 + o0] = pk;
        }
    }
    __syncthreads();
    for (int v = t; v < 768; v += 256) {
        int s = v / 12, g = v % 12;
        *(u16x8*)&hbuf[((size_t)b * HWn + hw0 + s) * Cn + g * 8] = *(const u16x8*)&Hs[s * 104 + g * 8];
    }
}

// ---------------- grapher: cat -> fcg+BN+GELU -> fc2+BN+residual -> r (bf16, in-place over h) ----------------
__global__ __launch_bounds__(256) void grapher_kernel(
    const ushort* __restrict__ hbuf, const float* __restrict__ Xres,
    const ushort* __restrict__ wgp, const ushort* __restrict__ w2p,
    const float* __restrict__ prm,
    const float* __restrict__ cmin2, const float* __restrict__ rmin2,
    ushort* __restrict__ rbuf)
{
    __shared__ __align__(16) ushort Xs[64 * 200];  // cat tile [s][192], pad->200
    __shared__ __align__(16) ushort Gs[64 * 200];  // g tile
    int bid = blockIdx.x, b = bid / TPI, hw0 = (bid % TPI) * NT;
    int t = threadIdx.x, lane = t & 63, wave = t >> 6;
    int wm = wave >> 1, wn = wave & 1, q = lane >> 4, sl = lane & 15;

    // stage cat tile
    for (int v = t; v < 768; v += 256) {
        int s = v / 12, g = v % 12;
        u16x8 hv = *(const u16x8*)&hbuf[((size_t)b * HWn + hw0 + s) * Cn + g * 8];
        *(u16x8*)&Xs[s * 200 + g * 8] = hv;
        int pos = hw0 + s, i = pos / Wn, j = pos - i * Wn;
        const float* cm = &cmin2[(((size_t)b * 112 + j) * 2 + (i & 1)) * 96 + g * 8];
        const float* rm = &rmin2[(((size_t)b * 112 + i) * 2 + (j & 1)) * 96 + g * 8];
        union { u16x8 v; ushort u[8]; } hh, xx;
        hh.v = hv;
        #pragma unroll
        for (int e = 0; e < 8; ++e) {
            float hf = bf2f(hh.u[e]);
            xx.u[e] = f2bf(fmaxf(hf - cm[e], hf - rm[e]));  // mins include self => >= 0
        }
        *(u16x8*)&Xs[s * 200 + 96 + g * 8] = xx.v;
    }
    __syncthreads();

    // fcg: M=192 (wave: 6 mt), K=192 (6 kc), N: 2 cols of 16 per wave
    f32x4 acc[6][2] = {};
    #pragma unroll
    for (int kc = 0; kc < 6; ++kc) {
        bf16x8 b0 = *(const bf16x8*)&Xs[(wn * 32 + sl) * 200 + kc * 32 + q * 8];
        bf16x8 b1 = *(const bf16x8*)&Xs[(wn * 32 + 16 + sl) * 200 + kc * 32 + q * 8];
        #pragma unroll
        for (int m = 0; m < 6; ++m) {
            bf16x8 af = *(const bf16x8*)&wgp[(((wm * 6 + m) * 6 + kc) * 64 + lane) * 8];
            acc[m][0] = MFMA16(af, b0, acc[m][0]);
            acc[m][1] = MFMA16(af, b1, acc[m][1]);
        }
    }
    #pragma unroll
    for (int m = 0; m < 6; ++m) {
        int o0 = (wm * 6 + m) * 16 + q * 4;
        f32x4 a4 = *(const f32x4*)&prm[192 + o0];
        f32x4 s4 = *(const f32x4*)&prm[384 + o0];
        #pragma unroll
        for (int nc = 0; nc < 2; ++nc) {
            int srow = wn * 32 + nc * 16 + sl;
            ushort4 pk;
            pk.x = f2bf(gelu_f(acc[m][nc][0] * a4[0] + s4[0]));
            pk.y = f2bf(gelu_f(acc[m][nc][1] * a4[1] + s4[1]));
            pk.z = f2bf(gelu_f(acc[m][nc][2] * a4[2] + s4[2]));
            pk.w = f2bf(gelu_f(acc[m][nc][3] * a4[3] + s4[3]));
            *(ushort4*)&Gs[srow * 200 + o0] = pk;
        }
    }
    __syncthreads();

    // fc2: M=96 (wave: 3 mt), K=192 (6 kc)
    f32x4 acc2[3][2] = {};
    #pragma unroll
    for (int kc = 0; kc < 6; ++kc) {
        bf16x8 b0 = *(const bf16x8*)&Gs[(wn * 32 + sl) * 200 + kc * 32 + q * 8];
        bf16x8 b1 = *(const bf16x8*)&Gs[(wn * 32 + 16 + sl) * 200 + kc * 32 + q * 8];
        #pragma unroll
        for (int m = 0; m < 3; ++m) {
            bf16x8 af = *(const bf16x8*)&w2p[(((wm * 3 + m) * 6 + kc) * 64 + lane) * 8];
            acc2[m][0] = MFMA16(af, b0, acc2[m][0]);
            acc2[m][1] = MFMA16(af, b1, acc2[m][1]);
        }
    }
    #pragma unroll
    for (int m = 0; m < 3; ++m) {
        int o0 = (wm * 3 + m) * 16 + q * 4;
        f32x4 a4 = *(const f32x4*)&prm[576 + o0];
        f32x4 s4 = *(const f32x4*)&prm[672 + o0];
        #pragma unroll
        for (int nc = 0; nc < 2; ++nc) {
            int srow = wn * 32 + nc * 16 + sl, sgl = hw0 + srow;
            ushort4 pk;
            float r0 = acc2[m][nc][0] * a4[0] + s4[0] + Xres[((size_t)b * Cn + o0 + 0) * HWn + sgl];
            float r1 = acc2[m][nc][1] * a4[1] + s4[1] + Xres[((size_t)b * Cn + o0 + 1) * HWn + sgl];
            float r2 = acc2[m][nc][2] * a4[2] + s4[2] + Xres[((size_t)b * Cn + o0 + 2) * HWn + sgl];
            float r3 = acc2[m][nc][3] * a4[3] + s4[3] + Xres[((size_t)b * Cn + o0 + 3) * HWn + sgl];
            pk.x = f2bf(r0); pk.y = f2bf(r1); pk.z = f2bf(r2); pk.w = f2bf(r3);
            *(ushort4*)&Xs[srow * 200 + o0] = pk;   // reuse Xs as r-tile
        }
    }
    __syncthreads();
    for (int v = t; v < 768; v += 256) {
        int s = v / 12, g = v % 12;
        *(u16x8*)&rbuf[((size_t)b * HWn + hw0 + s) * Cn + g * 8] = *(const u16x8*)&Xs[s * 200 + g * 8];
    }
}

// ---------------- FFN: out = Wf2 gelu(Wf1 r + bf1) + bf2, fp32 [b][c][hw] ----------------
__global__ __launch_bounds__(256) void ffn_kernel(
    const ushort* __restrict__ rbuf,
    const ushort* __restrict__ wf1p, const float* __restrict__ bf1,
    const ushort* __restrict__ wf2p, const float* __restrict__ bf2,
    float* __restrict__ Out)
{
    __shared__ __align__(16) ushort Rs[64 * 104];   // 13.3 KB
    __shared__ __align__(16) ushort Mid[64 * 392];  // 50.2 KB
    int bid = blockIdx.x, b = bid / TPI, hw0 = (bid % TPI) * NT;
    int t = threadIdx.x, lane = t & 63, wave = t >> 6;
    int wm = wave >> 1, wn = wave & 1, q = lane >> 4, sl = lane & 15;

    for (int v = t; v < 768; v += 256) {
        int s = v / 12, g = v % 12;
        *(u16x8*)&Rs[s * 104 + g * 8] = *(const u16x8*)&rbuf[((size_t)b * HWn + hw0 + s) * Cn + g * 8];
    }
    __syncthreads();

    // ffn1: M=384 (wave: 12 mt), K=96 (3 kc)
    f32x4 acc[12][2] = {};
    #pragma unroll
    for (int kc = 0; kc < 3; ++kc) {
        bf16x8 b0 = *(const bf16x8*)&Rs[(wn * 32 + sl) * 104 + kc * 32 + q * 8];
        bf16x8 b1 = *(const bf16x8*)&Rs[(wn * 32 + 16 + sl) * 104 + kc * 32 + q * 8];
        #pragma unroll
        for (int m = 0; m < 12; ++m) {
            bf16x8 af = *(const bf16x8*)&wf1p[(((wm * 12 + m) * 3 + kc) * 64 + lane) * 8];
            acc[m][0] = MFMA16(af, b0, acc[m][0]);
            acc[m][1] = MFMA16(af, b1, acc[m][1]);
        }
    }
    #pragma unroll
    for (int m = 0; m < 12; ++m) {
        int o0 = (wm * 12 + m) * 16 + q * 4;
        f32x4 b4 = *(const f32x4*)&bf1[o0];
        #pragma unroll
        for (int nc = 0; nc < 2; ++nc) {
            int srow = wn * 32 + nc * 16 + sl;
            ushort4 pk;
            pk.x = f2bf(gelu_f(acc[m][nc][0] + b4[0]));
            pk.y = f2bf(gelu_f(acc[m][nc][1] + b4[1]));
            pk.z = f2bf(gelu_f(acc[m][nc][2] + b4[2]));
            pk.w = f2bf(gelu_f(acc[m][nc][3] + b4[3]));
            *(ushort4*)&Mid[srow * 392 + o0] = pk;
        }
    }
    __syncthreads();

    // ffn2: M=96 (wave: 3 mt), K=384 (12 kc)
    f32x4 acc2[3][2] = {};
    #pragma unroll
    for (int kc = 0; kc < 12; ++kc) {
        bf16x8 b0 = *(const bf16x8*)&Mid[(wn * 32 + sl) * 392 + kc * 32 + q * 8];
        bf16x8 b1 = *(const bf16x8*)&Mid[(wn * 32 + 16 + sl) * 392 + kc * 32 + q * 8];
        #pragma unroll
        for (int m = 0; m < 3; ++m) {
            bf16x8 af = *(const bf16x8*)&wf2p[(((wm * 3 + m) * 12 + kc) * 64 + lane) * 8];
            acc2[m][0] = MFMA16(af, b0, acc2[m][0]);
            acc2[m][1] = MFMA16(af, b1, acc2[m][1]);
        }
    }
    #pragma unroll
    for (int m = 0; m < 3; ++m) {
        int o0 = (wm * 3 + m) * 16 + q * 4;
        f32x4 b4 = *(const f32x4*)&bf2[o0];
        #pragma unroll
        for (int nc = 0; nc < 2; ++nc) {
            int sgl = hw0 + wn * 32 + nc * 16 + sl;
            Out[((size_t)b * Cn + o0 + 0) * HWn + sgl] = acc2[m][nc][0] + b4[0];
            Out[((size_t)b * Cn + o0 + 1) * HWn + sgl] = acc2[m][nc][1] + b4[1];
            Out[((size_t)b * Cn + o0 + 2) * HWn + sgl] = acc2[m][nc][2] + b4[2];
            Out[((size_t)b * Cn + o0 + 3) * HWn + sgl] = acc2[m][nc][3] + b4[3];
        }
    }
}

extern "C" void kernel_launch(void* const* d_in, const int* in_sizes, int n_in,
                              void* d_out, int out_size, void* d_ws, size_t ws_size,
                              hipStream_t stream) {
    (void)in_sizes; (void)n_in; (void)out_size; (void)ws_size;
    const float* x   = (const float*)d_in[0];
    const float* w1  = (const float*)d_in[1];
    const float* b1  = (const float*)d_in[2];
    const float* g1  = (const float*)d_in[3];
    const float* be1 = (const float*)d_in[4];
    const float* m1  = (const float*)d_in[5];
    const float* v1  = (const float*)d_in[6];
    const float* wg  = (const float*)d_in[7];
    const float* bg  = (const float*)d_in[8];
    const float* gg  = (const float*)d_in[9];
    const float* beg = (const float*)d_in[10];
    const float* mg  = (const float*)d_in[11];
    const float* vg  = (const float*)d_in[12];
    const float* w2  = (const float*)d_in[13];
    const float* b2  = (const float*)d_in[14];
    const float* g2  = (const float*)d_in[15];
    const float* be2 = (const float*)d_in[16];
    const float* m2  = (const float*)d_in[17];
    const float* v2  = (const float*)d_in[18];
    const float* wf1 = (const float*)d_in[19];
    const float* bf1 = (const float*)d_in[20];
    const float* wf2 = (const float*)d_in[21];
    const float* bf2 = (const float*)d_in[22];
    float* out = (float*)d_out;

    // ---- ws layout ----
    char* base = (char*)d_ws;
    const size_t H_BYTES   = (size_t)Bn * HWn * Cn * 2;        // 38,535,168
    const size_t MIN_BYTES = (size_t)Bn * 112 * 2 * 96 * 4;    // 1,376,256
    ushort* hbuf  = (ushort*)base;                              // h, later r (in-place)
    float*  rmin2 = (float*)(base + H_BYTES);
    float*  cmin2 = (float*)(base + H_BYTES + MIN_BYTES);
    float*  prm   = (float*)(base + H_BYTES + 2 * MIN_BYTES);
    ushort* wpack = (ushort*)(base + H_BYTES + 2 * MIN_BYTES + 3072);
    ushort* w1p  = wpack;
    ushort* wgp  = wpack + 9216;
    ushort* w2p  = wpack + 46080;
    ushort* wf1p = wpack + 64512;
    ushort* wf2p = wpack + 101376;

    params_kernel<<<dim3(1), dim3(256), 0, stream>>>(
        b1, g1, be1, m1, v1, bg, gg, beg, mg, vg, b2, g2, be2, m2, v2, prm);
    pack_kernel<<<dim3(540), dim3(256), 0, stream>>>(w1, wg, w2, wf1, wf2, wpack);

    dim3 grid(Bn * TPI), blk(256);
    fc1_kernel<<<grid, blk, 0, stream>>>(x, w1p, prm, hbuf);
    mins_kernel<<<dim3(Bn * 2 * 112), blk, 0, stream>>>(hbuf, rmin2, cmin2);
    grapher_kernel<<<grid, blk, 0, stream>>>(hbuf, x, wgp, w2p, prm, cmin2, rmin2, hbuf);
    ffn_kernel<<<grid, blk, 0, stream>>>(hbuf, wf1p, bf1, wf2p, bf2, out);
}

// Round 4
// 211.522 us; speedup vs baseline: 8.0986x; 1.4636x over previous
//
#include <hip/hip_runtime.h>
#include <hip/hip_bf16.h>
#include <math.h>

#define EPSC 1e-5f

typedef __attribute__((ext_vector_type(8))) short bf16x8;
typedef __attribute__((ext_vector_type(4))) float f32x4;
typedef __attribute__((ext_vector_type(8))) unsigned short u16x8;

constexpr int Bn = 16, Cn = 96, Hn = 112, Wn = 112, HWn = Hn * Wn; // 12544
constexpr int NT = 64, TPI = HWn / NT;                             // 196

#define MFMA16(a, b, c) __builtin_amdgcn_mfma_f32_16x16x32_bf16((a), (b), (c), 0, 0, 0)

__device__ __forceinline__ ushort f2bf(float f) {
    __hip_bfloat16 h = __float2bfloat16(f);
    return __builtin_bit_cast(ushort, h);
}
__device__ __forceinline__ float bf2f(ushort u) {
    return __builtin_bit_cast(float, (unsigned)u << 16);
}
// tanh-form GELU: x * sigmoid(1.5957691*x + 0.0713548*x^3); |err| <= ~3e-4
__device__ __forceinline__ float gelu_f(float x) {
    float t = x * x;
    float z = x * fmaf(0.0713548162726f, t, 1.59576912161f);
    float e = __expf(-z);
    return __fdividef(x, 1.0f + e);
}

// ---------------- BN folding ----------------
// prm: A1[0:96] B1[96:192] Ag[192:384] Bg[384:576] A2[576:672] B2[672:768]
__global__ __launch_bounds__(256) void params_kernel(
    const float* __restrict__ b1, const float* __restrict__ g1, const float* __restrict__ be1,
    const float* __restrict__ m1, const float* __restrict__ v1,
    const float* __restrict__ bg, const float* __restrict__ gg, const float* __restrict__ beg,
    const float* __restrict__ mg, const float* __restrict__ vg,
    const float* __restrict__ b2, const float* __restrict__ g2, const float* __restrict__ be2,
    const float* __restrict__ m2, const float* __restrict__ v2,
    float* __restrict__ P)
{
    int t = threadIdx.x;
    if (t < 96) {
        float s = g1[t] * rsqrtf(v1[t] + EPSC);
        P[t]       = s;
        P[96 + t]  = (b1[t] - m1[t]) * s + be1[t];
        float s2 = g2[t] * rsqrtf(v2[t] + EPSC);
        P[576 + t] = s2;
        P[672 + t] = (b2[t] - m2[t]) * s2 + be2[t];
    }
    if (t < 192) {
        float s = gg[t] * rsqrtf(vg[t] + EPSC);
        P[192 + t] = s;
        P[384 + t] = (bg[t] - mg[t]) * s + beg[t];
    }
}

// ---------------- weight pack: fragment order [mt][kc][lane][8], bf16 ----------------
__global__ __launch_bounds__(256) void pack_kernel(
    const float* __restrict__ w1, const float* __restrict__ wg, const float* __restrict__ w2,
    const float* __restrict__ wf1, const float* __restrict__ wf2,
    ushort* __restrict__ dst)
{
    int idx = blockIdx.x * 256 + threadIdx.x;
    if (idx >= 138240) return;
    const float* src; int K, off;
    if      (idx <   9216) { src = w1;  K =  96; off = 0;      }
    else if (idx <  46080) { src = wg;  K = 192; off = 9216;   }
    else if (idx <  64512) { src = w2;  K = 192; off = 46080;  }
    else if (idx < 101376) { src = wf1; K =  96; off = 64512;  }
    else                   { src = wf2; K = 384; off = 101376; }
    int r = idx - off;
    int e = r & 7, lane = (r >> 3) & 63, tile = r >> 9;
    int KC = K / 32;
    int kc = tile % KC, mt = tile / KC;
    int row = mt * 16 + (lane & 15);
    int col = kc * 32 + (lane >> 4) * 8 + e;
    dst[idx] = f2bf(src[(size_t)row * K + col]);
}

// ---------------- parity mins ----------------
__global__ __launch_bounds__(256) void mins_kernel(
    const ushort* __restrict__ h, float* __restrict__ rmin2, float* __restrict__ cmin2)
{
    __shared__ __align__(16) ushort sl[112 * 96];
    int bid = blockIdx.x;            // Bn * 2 * 112
    int b = bid / 224, rem = bid % 224, mode = rem / 112, line = rem % 112;
    int t = threadIdx.x;
    if (mode == 0) {
        const ushort* base = h + ((size_t)b * HWn + line * Wn) * Cn;
        for (int v = t; v < 1344; v += 256)
            *(u16x8*)&sl[v * 8] = *(const u16x8*)&base[v * 8];
    } else {
        for (int v = t; v < 1344; v += 256) {
            int i = v / 12, g = v % 12;
            *(u16x8*)&sl[(i * 12 + g) * 8] =
                *(const u16x8*)&h[((size_t)b * HWn + i * Wn + line) * Cn + g * 8];
        }
    }
    __syncthreads();
    if (t < 192) {
        int c = t % 96, p = t / 96;
        float m = 1e30f;
        #pragma unroll 8
        for (int n = 0; n < 56; ++n) m = fminf(m, bf2f(sl[(p + 2 * n) * 96 + c]));
        float* dst = (mode == 0) ? rmin2 : cmin2;
        dst[(((size_t)b * 112 + line) * 2 + p) * 96 + c] = m;
    }
}

// ---------------- fc1: h = BN(W1 x) -> bf16 [b][hw][96] ----------------
__global__ __launch_bounds__(256) void fc1_kernel(
    const float* __restrict__ X, const ushort* __restrict__ w1p,
    const float* __restrict__ prm, ushort* __restrict__ hbuf)
{
    __shared__ __align__(16) ushort Hs[64 * 104];
    int bid = blockIdx.x, b = bid / TPI, hw0 = (bid % TPI) * NT;
    int t = threadIdx.x, lane = t & 63, wave = t >> 6;
    int wm = wave >> 1, wn = wave & 1, q = lane >> 4, sl = lane & 15;

    bf16x8 bfr[3][2];
    #pragma unroll
    for (int kc = 0; kc < 3; ++kc)
        #pragma unroll
        for (int nc = 0; nc < 2; ++nc) {
            int s = hw0 + wn * 32 + nc * 16 + sl;
            union { bf16x8 v; ushort u[8]; } f;
            #pragma unroll
            for (int e = 0; e < 8; ++e) {
                int c = kc * 32 + q * 8 + e;
                f.u[e] = f2bf(X[((size_t)b * Cn + c) * HWn + s]);
            }
            bfr[kc][nc] = f.v;
        }
    f32x4 acc[3][2] = {};
    #pragma unroll
    for (int kc = 0; kc < 3; ++kc)
        #pragma unroll
        for (int m = 0; m < 3; ++m) {
            bf16x8 af = *(const bf16x8*)&w1p[(((wm * 3 + m) * 3 + kc) * 64 + lane) * 8];
            acc[m][0] = MFMA16(af, bfr[kc][0], acc[m][0]);
            acc[m][1] = MFMA16(af, bfr[kc][1], acc[m][1]);
        }
    #pragma unroll
    for (int m = 0; m < 3; ++m) {
        int o0 = (wm * 3 + m) * 16 + q * 4;
        f32x4 a4 = *(const f32x4*)&prm[o0];
        f32x4 s4 = *(const f32x4*)&prm[96 + o0];
        #pragma unroll
        for (int nc = 0; nc < 2; ++nc) {
            int srow = wn * 32 + nc * 16 + sl;
            ushort4 pk;
            pk.x = f2bf(acc[m][nc][0] * a4[0] + s4[0]);
            pk.y = f2bf(acc[m][nc][1] * a4[1] + s4[1]);
            pk.z = f2bf(acc[m][nc][2] * a4[2] + s4[2]);
            pk.w = f2bf(acc[m][nc][3] * a4[3] + s4[3]);
            *(ushort4*)&Hs[srow * 104 + o0] = pk;
        }
    }
    __syncthreads();
    for (int v = t; v < 768; v += 256) {
        int s = v / 12, g = v % 12;
        *(u16x8*)&hbuf[((size_t)b * HWn + hw0 + s) * Cn + g * 8] = *(const u16x8*)&Hs[s * 104 + g * 8];
    }
}

// ---------------- grapher: cat -> fcg+BN+GELU -> fc2+BN+residual -> r (bf16, in-place over h) ----------------
__global__ __launch_bounds__(256) void grapher_kernel(
    const ushort* __restrict__ hbuf, const float* __restrict__ Xres,
    const ushort* __restrict__ wgp, const ushort* __restrict__ w2p,
    const float* __restrict__ prm,
    const float* __restrict__ cmin2, const float* __restrict__ rmin2,
    ushort* __restrict__ rbuf)
{
    __shared__ __align__(16) ushort Xs[64 * 200];
    __shared__ __align__(16) ushort Gs[64 * 200];
    int bid = blockIdx.x, b = bid / TPI, hw0 = (bid % TPI) * NT;
    int t = threadIdx.x, lane = t & 63, wave = t >> 6;
    int wm = wave >> 1, wn = wave & 1, q = lane >> 4, sl = lane & 15;

    for (int v = t; v < 768; v += 256) {
        int s = v / 12, g = v % 12;
        u16x8 hv = *(const u16x8*)&hbuf[((size_t)b * HWn + hw0 + s) * Cn + g * 8];
        *(u16x8*)&Xs[s * 200 + g * 8] = hv;
        int pos = hw0 + s, i = pos / Wn, j = pos - i * Wn;
        const float* cm = &cmin2[(((size_t)b * 112 + j) * 2 + (i & 1)) * 96 + g * 8];
        const float* rm = &rmin2[(((size_t)b * 112 + i) * 2 + (j & 1)) * 96 + g * 8];
        union { u16x8 v; ushort u[8]; } hh, xx;
        hh.v = hv;
        #pragma unroll
        for (int e = 0; e < 8; ++e) {
            float hf = bf2f(hh.u[e]);
            xx.u[e] = f2bf(fmaxf(hf - cm[e], hf - rm[e]));
        }
        *(u16x8*)&Xs[s * 200 + 96 + g * 8] = xx.v;
    }
    __syncthreads();

    // fcg: M=192, K=192
    f32x4 acc[6][2] = {};
    #pragma unroll
    for (int kc = 0; kc < 6; ++kc) {
        bf16x8 b0 = *(const bf16x8*)&Xs[(wn * 32 + sl) * 200 + kc * 32 + q * 8];
        bf16x8 b1 = *(const bf16x8*)&Xs[(wn * 32 + 16 + sl) * 200 + kc * 32 + q * 8];
        #pragma unroll
        for (int m = 0; m < 6; ++m) {
            bf16x8 af = *(const bf16x8*)&wgp[(((wm * 6 + m) * 6 + kc) * 64 + lane) * 8];
            acc[m][0] = MFMA16(af, b0, acc[m][0]);
            acc[m][1] = MFMA16(af, b1, acc[m][1]);
        }
    }
    #pragma unroll
    for (int m = 0; m < 6; ++m) {
        int o0 = (wm * 6 + m) * 16 + q * 4;
        f32x4 a4 = *(const f32x4*)&prm[192 + o0];
        f32x4 s4 = *(const f32x4*)&prm[384 + o0];
        #pragma unroll
        for (int nc = 0; nc < 2; ++nc) {
            int srow = wn * 32 + nc * 16 + sl;
            ushort4 pk;
            pk.x = f2bf(gelu_f(acc[m][nc][0] * a4[0] + s4[0]));
            pk.y = f2bf(gelu_f(acc[m][nc][1] * a4[1] + s4[1]));
            pk.z = f2bf(gelu_f(acc[m][nc][2] * a4[2] + s4[2]));
            pk.w = f2bf(gelu_f(acc[m][nc][3] * a4[3] + s4[3]));
            *(ushort4*)&Gs[srow * 200 + o0] = pk;
        }
    }
    __syncthreads();

    // fc2: M=96, K=192
    f32x4 acc2[3][2] = {};
    #pragma unroll
    for (int kc = 0; kc < 6; ++kc) {
        bf16x8 b0 = *(const bf16x8*)&Gs[(wn * 32 + sl) * 200 + kc * 32 + q * 8];
        bf16x8 b1 = *(const bf16x8*)&Gs[(wn * 32 + 16 + sl) * 200 + kc * 32 + q * 8];
        #pragma unroll
        for (int m = 0; m < 3; ++m) {
            bf16x8 af = *(const bf16x8*)&w2p[(((wm * 3 + m) * 6 + kc) * 64 + lane) * 8];
            acc2[m][0] = MFMA16(af, b0, acc2[m][0]);
            acc2[m][1] = MFMA16(af, b1, acc2[m][1]);
        }
    }
    #pragma unroll
    for (int m = 0; m < 3; ++m) {
        int o0 = (wm * 3 + m) * 16 + q * 4;
        f32x4 a4 = *(const f32x4*)&prm[576 + o0];
        f32x4 s4 = *(const f32x4*)&prm[672 + o0];
        #pragma unroll
        for (int nc = 0; nc < 2; ++nc) {
            int srow = wn * 32 + nc * 16 + sl, sgl = hw0 + srow;
            ushort4 pk;
            float r0 = acc2[m][nc][0] * a4[0] + s4[0] + Xres[((size_t)b * Cn + o0 + 0) * HWn + sgl];
            float r1 = acc2[m][nc][1] * a4[1] + s4[1] + Xres[((size_t)b * Cn + o0 + 1) * HWn + sgl];
            float r2 = acc2[m][nc][2] * a4[2] + s4[2] + Xres[((size_t)b * Cn + o0 + 2) * HWn + sgl];
            float r3 = acc2[m][nc][3] * a4[3] + s4[3] + Xres[((size_t)b * Cn + o0 + 3) * HWn + sgl];
            pk.x = f2bf(r0); pk.y = f2bf(r1); pk.z = f2bf(r2); pk.w = f2bf(r3);
            *(ushort4*)&Xs[srow * 200 + o0] = pk;
        }
    }
    __syncthreads();
    for (int v = t; v < 768; v += 256) {
        int s = v / 12, g = v % 12;
        *(u16x8*)&rbuf[((size_t)b * HWn + hw0 + s) * Cn + g * 8] = *(const u16x8*)&Xs[s * 200 + g * 8];
    }
}

// ---------------- FFN (chunked): out = Wf2 gelu(Wf1 r + bf1) + bf2 ----------------
// mid computed in 4 chunks of 96 channels; each chunk immediately consumed by
// the second GEMM (double-buffered 13 KB chunk slab, 1 barrier per chunk).
__global__ __launch_bounds__(256) void ffn_kernel(
    const ushort* __restrict__ rbuf,
    const ushort* __restrict__ wf1p, const float* __restrict__ bf1,
    const ushort* __restrict__ wf2p, const float* __restrict__ bf2,
    float* __restrict__ Out)
{
    __shared__ __align__(16) ushort Rs[64 * 104];       // 13.3 KB
    __shared__ __align__(16) ushort Mc[2][64 * 104];    // 26.6 KB
    int bid = blockIdx.x, b = bid / TPI, hw0 = (bid % TPI) * NT;
    int t = threadIdx.x, lane = t & 63, wave = t >> 6;
    int wm = wave >> 1, wn = wave & 1, q = lane >> 4, sl = lane & 15;

    for (int v = t; v < 768; v += 256) {
        int s = v / 12, g = v % 12;
        *(u16x8*)&Rs[s * 104 + g * 8] = *(const u16x8*)&rbuf[((size_t)b * HWn + hw0 + s) * Cn + g * 8];
    }
    __syncthreads();

    // hoist r B-frags to registers (reused by all 4 chunks)
    bf16x8 rb[3][2];
    #pragma unroll
    for (int kc = 0; kc < 3; ++kc) {
        rb[kc][0] = *(const bf16x8*)&Rs[(wn * 32 + sl) * 104 + kc * 32 + q * 8];
        rb[kc][1] = *(const bf16x8*)&Rs[(wn * 32 + 16 + sl) * 104 + kc * 32 + q * 8];
    }

    f32x4 acc2[3][2] = {};
    for (int c = 0; c < 4; ++c) {
        // ffn1 slice: global mt = c*6 + wm*3 + m, K=96 (3 kc)
        f32x4 a1[3][2] = {};
        #pragma unroll
        for (int kc = 0; kc < 3; ++kc)
            #pragma unroll
            for (int m = 0; m < 3; ++m) {
                bf16x8 af = *(const bf16x8*)&wf1p[(((c * 6 + wm * 3 + m) * 3 + kc) * 64 + lane) * 8];
                a1[m][0] = MFMA16(af, rb[kc][0], a1[m][0]);
                a1[m][1] = MFMA16(af, rb[kc][1], a1[m][1]);
            }
        // epilogue: gelu -> chunk slab
        ushort* mc = (ushort*)Mc[c & 1];
        #pragma unroll
        for (int m = 0; m < 3; ++m) {
            int ol = (wm * 3 + m) * 16 + q * 4;          // 0..95 within chunk
            f32x4 b4 = *(const f32x4*)&bf1[c * 96 + ol];
            #pragma unroll
            for (int nc = 0; nc < 2; ++nc) {
                int srow = wn * 32 + nc * 16 + sl;
                ushort4 pk;
                pk.x = f2bf(gelu_f(a1[m][nc][0] + b4[0]));
                pk.y = f2bf(gelu_f(a1[m][nc][1] + b4[1]));
                pk.z = f2bf(gelu_f(a1[m][nc][2] + b4[2]));
                pk.w = f2bf(gelu_f(a1[m][nc][3] + b4[3]));
                *(ushort4*)&mc[srow * 104 + ol] = pk;
            }
        }
        __syncthreads();
        // ffn2 partial accumulation over this chunk (global kc = c*3 + kc)
        #pragma unroll
        for (int kc = 0; kc < 3; ++kc) {
            bf16x8 m0 = *(const bf16x8*)&mc[(wn * 32 + sl) * 104 + kc * 32 + q * 8];
            bf16x8 m1 = *(const bf16x8*)&mc[(wn * 32 + 16 + sl) * 104 + kc * 32 + q * 8];
            #pragma unroll
            for (int m = 0; m < 3; ++m) {
                bf16x8 af = *(const bf16x8*)&wf2p[(((wm * 3 + m) * 12 + c * 3 + kc) * 64 + lane) * 8];
                acc2[m][0] = MFMA16(af, m0, acc2[m][0]);
                acc2[m][1] = MFMA16(af, m1, acc2[m][1]);
            }
        }
        // no second barrier: next chunk writes the other slab; the barrier in
        // the next iteration orders those reads/writes (double-buffer proof in notes)
    }
    #pragma unroll
    for (int m = 0; m < 3; ++m) {
        int o0 = (wm * 3 + m) * 16 + q * 4;
        f32x4 b4 = *(const f32x4*)&bf2[o0];
        #pragma unroll
        for (int nc = 0; nc < 2; ++nc) {
            int sgl = hw0 + wn * 32 + nc * 16 + sl;
            Out[((size_t)b * Cn + o0 + 0) * HWn + sgl] = acc2[m][nc][0] + b4[0];
            Out[((size_t)b * Cn + o0 + 1) * HWn + sgl] = acc2[m][nc][1] + b4[1];
            Out[((size_t)b * Cn + o0 + 2) * HWn + sgl] = acc2[m][nc][2] + b4[2];
            Out[((size_t)b * Cn + o0 + 3) * HWn + sgl] = acc2[m][nc][3] + b4[3];
        }
    }
}

extern "C" void kernel_launch(void* const* d_in, const int* in_sizes, int n_in,
                              void* d_out, int out_size, void* d_ws, size_t ws_size,
                              hipStream_t stream) {
    (void)in_sizes; (void)n_in; (void)out_size; (void)ws_size;
    const float* x   = (const float*)d_in[0];
    const float* w1  = (const float*)d_in[1];
    const float* b1  = (const float*)d_in[2];
    const float* g1  = (const float*)d_in[3];
    const float* be1 = (const float*)d_in[4];
    const float* m1  = (const float*)d_in[5];
    const float* v1  = (const float*)d_in[6];
    const float* wg  = (const float*)d_in[7];
    const float* bg  = (const float*)d_in[8];
    const float* gg  = (const float*)d_in[9];
    const float* beg = (const float*)d_in[10];
    const float* mg  = (const float*)d_in[11];
    const float* vg  = (const float*)d_in[12];
    const float* w2  = (const float*)d_in[13];
    const float* b2  = (const float*)d_in[14];
    const float* g2  = (const float*)d_in[15];
    const float* be2 = (const float*)d_in[16];
    const float* m2  = (const float*)d_in[17];
    const float* v2  = (const float*)d_in[18];
    const float* wf1 = (const float*)d_in[19];
    const float* bf1 = (const float*)d_in[20];
    const float* wf2 = (const float*)d_in[21];
    const float* bf2 = (const float*)d_in[22];
    float* out = (float*)d_out;

    char* base = (char*)d_ws;
    const size_t H_BYTES   = (size_t)Bn * HWn * Cn * 2;
    const size_t MIN_BYTES = (size_t)Bn * 112 * 2 * 96 * 4;
    ushort* hbuf  = (ushort*)base;
    float*  rmin2 = (float*)(base + H_BYTES);
    float*  cmin2 = (float*)(base + H_BYTES + MIN_BYTES);
    float*  prm   = (float*)(base + H_BYTES + 2 * MIN_BYTES);
    ushort* wpack = (ushort*)(base + H_BYTES + 2 * MIN_BYTES + 3072);
    ushort* w1p  = wpack;
    ushort* wgp  = wpack + 9216;
    ushort* w2p  = wpack + 46080;
    ushort* wf1p = wpack + 64512;
    ushort* wf2p = wpack + 101376;

    params_kernel<<<dim3(1), dim3(256), 0, stream>>>(
        b1, g1, be1, m1, v1, bg, gg, beg, mg, vg, b2, g2, be2, m2, v2, prm);
    pack_kernel<<<dim3(540), dim3(256), 0, stream>>>(w1, wg, w2, wf1, wf2, wpack);

    dim3 grid(Bn * TPI), blk(256);
    fc1_kernel<<<grid, blk, 0, stream>>>(x, w1p, prm, hbuf);
    mins_kernel<<<dim3(Bn * 2 * 112), blk, 0, stream>>>(hbuf, rmin2, cmin2);
    grapher_kernel<<<grid, blk, 0, stream>>>(hbuf, x, wgp, w2p, prm, cmin2, rmin2, hbuf);
    ffn_kernel<<<grid, blk, 0, stream>>>(hbuf, wf1p, bf1, wf2p, bf2, out);
}

// Round 5
// 209.888 us; speedup vs baseline: 8.1617x; 1.0078x over previous
//
#include <hip/hip_runtime.h>
#include <hip/hip_bf16.h>
#include <math.h>

#define EPSC 1e-5f

typedef __attribute__((ext_vector_type(8))) short bf16x8;
typedef __attribute__((ext_vector_type(4))) float f32x4;
typedef __attribute__((ext_vector_type(8))) unsigned short u16x8;

constexpr int Bn = 16, Cn = 96, Hn = 112, Wn = 112, HWn = Hn * Wn; // 12544
constexpr int NT = 64, TPI = HWn / NT;                             // 196

#define MFMA16(a, b, c) __builtin_amdgcn_mfma_f32_16x16x32_bf16((a), (b), (c), 0, 0, 0)

__device__ __forceinline__ ushort f2bf(float f) {
    __hip_bfloat16 h = __float2bfloat16(f);
    return __builtin_bit_cast(ushort, h);
}
__device__ __forceinline__ float bf2f(ushort u) {
    return __builtin_bit_cast(float, (unsigned)u << 16);
}
// tanh-form GELU: x * sigmoid(1.5957691*x + 0.0713548*x^3); |err| <= ~3e-4
__device__ __forceinline__ float gelu_f(float x) {
    float t = x * x;
    float z = x * fmaf(0.0713548162726f, t, 1.59576912161f);
    float e = __expf(-z);
    return __fdividef(x, 1.0f + e);
}

// ---------------- BN folding ----------------
// prm: A1[0:96] B1[96:192] Ag[192:384] Bg[384:576] A2[576:672] B2[672:768]
__global__ __launch_bounds__(256) void params_kernel(
    const float* __restrict__ b1, const float* __restrict__ g1, const float* __restrict__ be1,
    const float* __restrict__ m1, const float* __restrict__ v1,
    const float* __restrict__ bg, const float* __restrict__ gg, const float* __restrict__ beg,
    const float* __restrict__ mg, const float* __restrict__ vg,
    const float* __restrict__ b2, const float* __restrict__ g2, const float* __restrict__ be2,
    const float* __restrict__ m2, const float* __restrict__ v2,
    float* __restrict__ P)
{
    int t = threadIdx.x;
    if (t < 96) {
        float s = g1[t] * rsqrtf(v1[t] + EPSC);
        P[t]       = s;
        P[96 + t]  = (b1[t] - m1[t]) * s + be1[t];
        float s2 = g2[t] * rsqrtf(v2[t] + EPSC);
        P[576 + t] = s2;
        P[672 + t] = (b2[t] - m2[t]) * s2 + be2[t];
    }
    if (t < 192) {
        float s = gg[t] * rsqrtf(vg[t] + EPSC);
        P[192 + t] = s;
        P[384 + t] = (bg[t] - mg[t]) * s + beg[t];
    }
}

// ---------------- weight pack: fragment order [mt][kc][lane][8], bf16 ----------------
__global__ __launch_bounds__(256) void pack_kernel(
    const float* __restrict__ w1, const float* __restrict__ wg, const float* __restrict__ w2,
    const float* __restrict__ wf1, const float* __restrict__ wf2,
    ushort* __restrict__ dst)
{
    int idx = blockIdx.x * 256 + threadIdx.x;
    if (idx >= 138240) return;
    const float* src; int K, off;
    if      (idx <   9216) { src = w1;  K =  96; off = 0;      }
    else if (idx <  46080) { src = wg;  K = 192; off = 9216;   }
    else if (idx <  64512) { src = w2;  K = 192; off = 46080;  }
    else if (idx < 101376) { src = wf1; K =  96; off = 64512;  }
    else                   { src = wf2; K = 384; off = 101376; }
    int r = idx - off;
    int e = r & 7, lane = (r >> 3) & 63, tile = r >> 9;
    int KC = K / 32;
    int kc = tile % KC, mt = tile / KC;
    int row = mt * 16 + (lane & 15);
    int col = kc * 32 + (lane >> 4) * 8 + e;
    dst[idx] = f2bf(src[(size_t)row * K + col]);
}

// ---------------- parity mins ----------------
__global__ __launch_bounds__(256) void mins_kernel(
    const ushort* __restrict__ h, float* __restrict__ rmin2, float* __restrict__ cmin2)
{
    __shared__ __align__(16) ushort sl[112 * 96];
    int bid = blockIdx.x;            // Bn * 2 * 112
    int b = bid / 224, rem = bid % 224, mode = rem / 112, line = rem % 112;
    int t = threadIdx.x;
    if (mode == 0) {
        const ushort* base = h + ((size_t)b * HWn + line * Wn) * Cn;
        for (int v = t; v < 1344; v += 256)
            *(u16x8*)&sl[v * 8] = *(const u16x8*)&base[v * 8];
    } else {
        for (int v = t; v < 1344; v += 256) {
            int i = v / 12, g = v % 12;
            *(u16x8*)&sl[(i * 12 + g) * 8] =
                *(const u16x8*)&h[((size_t)b * HWn + i * Wn + line) * Cn + g * 8];
        }
    }
    __syncthreads();
    if (t < 192) {
        int c = t % 96, p = t / 96;
        float m = 1e30f;
        #pragma unroll 8
        for (int n = 0; n < 56; ++n) m = fminf(m, bf2f(sl[(p + 2 * n) * 96 + c]));
        float* dst = (mode == 0) ? rmin2 : cmin2;
        dst[(((size_t)b * 112 + line) * 2 + p) * 96 + c] = m;
    }
}

// ---------------- fc1: h = BN(W1 x) -> bf16 [b][hw][96] ----------------
__global__ __launch_bounds__(256) void fc1_kernel(
    const float* __restrict__ X, const ushort* __restrict__ w1p,
    const float* __restrict__ prm, ushort* __restrict__ hbuf)
{
    __shared__ __align__(16) ushort Hs[64 * 104];
    int bid = blockIdx.x, b = bid / TPI, hw0 = (bid % TPI) * NT;
    int t = threadIdx.x, lane = t & 63, wave = t >> 6;
    int wm = wave >> 1, wn = wave & 1, q = lane >> 4, sl = lane & 15;

    bf16x8 bfr[3][2];
    #pragma unroll
    for (int kc = 0; kc < 3; ++kc)
        #pragma unroll
        for (int nc = 0; nc < 2; ++nc) {
            int s = hw0 + wn * 32 + nc * 16 + sl;
            union { bf16x8 v; ushort u[8]; } f;
            #pragma unroll
            for (int e = 0; e < 8; ++e) {
                int c = kc * 32 + q * 8 + e;
                f.u[e] = f2bf(X[((size_t)b * Cn + c) * HWn + s]);
            }
            bfr[kc][nc] = f.v;
        }
    f32x4 acc[3][2] = {};
    #pragma unroll
    for (int kc = 0; kc < 3; ++kc)
        #pragma unroll
        for (int m = 0; m < 3; ++m) {
            bf16x8 af = *(const bf16x8*)&w1p[(((wm * 3 + m) * 3 + kc) * 64 + lane) * 8];
            acc[m][0] = MFMA16(af, bfr[kc][0], acc[m][0]);
            acc[m][1] = MFMA16(af, bfr[kc][1], acc[m][1]);
        }
    #pragma unroll
    for (int m = 0; m < 3; ++m) {
        int o0 = (wm * 3 + m) * 16 + q * 4;
        f32x4 a4 = *(const f32x4*)&prm[o0];
        f32x4 s4 = *(const f32x4*)&prm[96 + o0];
        #pragma unroll
        for (int nc = 0; nc < 2; ++nc) {
            int srow = wn * 32 + nc * 16 + sl;
            ushort4 pk;
            pk.x = f2bf(acc[m][nc][0] * a4[0] + s4[0]);
            pk.y = f2bf(acc[m][nc][1] * a4[1] + s4[1]);
            pk.z = f2bf(acc[m][nc][2] * a4[2] + s4[2]);
            pk.w = f2bf(acc[m][nc][3] * a4[3] + s4[3]);
            *(ushort4*)&Hs[srow * 104 + o0] = pk;
        }
    }
    __syncthreads();
    for (int v = t; v < 768; v += 256) {
        int s = v / 12, g = v % 12;
        *(u16x8*)&hbuf[((size_t)b * HWn + hw0 + s) * Cn + g * 8] = *(const u16x8*)&Hs[s * 104 + g * 8];
    }
}

// ---------------- grapher: cat -> fcg+BN+GELU -> fc2+BN+residual -> r (bf16, in-place over h) ----------------
__global__ __launch_bounds__(256) void grapher_kernel(
    const ushort* __restrict__ hbuf, const float* __restrict__ Xres,
    const ushort* __restrict__ wgp, const ushort* __restrict__ w2p,
    const float* __restrict__ prm,
    const float* __restrict__ cmin2, const float* __restrict__ rmin2,
    ushort* __restrict__ rbuf)
{
    __shared__ __align__(16) ushort Xs[64 * 200];
    __shared__ __align__(16) ushort Gs[64 * 200];
    int bid = blockIdx.x, b = bid / TPI, hw0 = (bid % TPI) * NT;
    int t = threadIdx.x, lane = t & 63, wave = t >> 6;
    int wm = wave >> 1, wn = wave & 1, q = lane >> 4, sl = lane & 15;

    for (int v = t; v < 768; v += 256) {
        int s = v / 12, g = v % 12;
        u16x8 hv = *(const u16x8*)&hbuf[((size_t)b * HWn + hw0 + s) * Cn + g * 8];
        *(u16x8*)&Xs[s * 200 + g * 8] = hv;
        int pos = hw0 + s, i = pos / Wn, j = pos - i * Wn;
        const float* cm = &cmin2[(((size_t)b * 112 + j) * 2 + (i & 1)) * 96 + g * 8];
        const float* rm = &rmin2[(((size_t)b * 112 + i) * 2 + (j & 1)) * 96 + g * 8];
        union { u16x8 v; ushort u[8]; } hh, xx;
        hh.v = hv;
        #pragma unroll
        for (int e = 0; e < 8; ++e) {
            float hf = bf2f(hh.u[e]);
            xx.u[e] = f2bf(fmaxf(hf - cm[e], hf - rm[e]));
        }
        *(u16x8*)&Xs[s * 200 + 96 + g * 8] = xx.v;
    }
    __syncthreads();

    // fcg: M=192, K=192
    f32x4 acc[6][2] = {};
    #pragma unroll
    for (int kc = 0; kc < 6; ++kc) {
        bf16x8 b0 = *(const bf16x8*)&Xs[(wn * 32 + sl) * 200 + kc * 32 + q * 8];
        bf16x8 b1 = *(const bf16x8*)&Xs[(wn * 32 + 16 + sl) * 200 + kc * 32 + q * 8];
        #pragma unroll
        for (int m = 0; m < 6; ++m) {
            bf16x8 af = *(const bf16x8*)&wgp[(((wm * 6 + m) * 6 + kc) * 64 + lane) * 8];
            acc[m][0] = MFMA16(af, b0, acc[m][0]);
            acc[m][1] = MFMA16(af, b1, acc[m][1]);
        }
    }
    #pragma unroll
    for (int m = 0; m < 6; ++m) {
        int o0 = (wm * 6 + m) * 16 + q * 4;
        f32x4 a4 = *(const f32x4*)&prm[192 + o0];
        f32x4 s4 = *(const f32x4*)&prm[384 + o0];
        #pragma unroll
        for (int nc = 0; nc < 2; ++nc) {
            int srow = wn * 32 + nc * 16 + sl;
            ushort4 pk;
            pk.x = f2bf(gelu_f(acc[m][nc][0] * a4[0] + s4[0]));
            pk.y = f2bf(gelu_f(acc[m][nc][1] * a4[1] + s4[1]));
            pk.z = f2bf(gelu_f(acc[m][nc][2] * a4[2] + s4[2]));
            pk.w = f2bf(gelu_f(acc[m][nc][3] * a4[3] + s4[3]));
            *(ushort4*)&Gs[srow * 200 + o0] = pk;
        }
    }
    __syncthreads();

    // fc2: M=96, K=192
    f32x4 acc2[3][2] = {};
    #pragma unroll
    for (int kc = 0; kc < 6; ++kc) {
        bf16x8 b0 = *(const bf16x8*)&Gs[(wn * 32 + sl) * 200 + kc * 32 + q * 8];
        bf16x8 b1 = *(const bf16x8*)&Gs[(wn * 32 + 16 + sl) * 200 + kc * 32 + q * 8];
        #pragma unroll
        for (int m = 0; m < 3; ++m) {
            bf16x8 af = *(const bf16x8*)&w2p[(((wm * 3 + m) * 6 + kc) * 64 + lane) * 8];
            acc2[m][0] = MFMA16(af, b0, acc2[m][0]);
            acc2[m][1] = MFMA16(af, b1, acc2[m][1]);
        }
    }
    #pragma unroll
    for (int m = 0; m < 3; ++m) {
        int o0 = (wm * 3 + m) * 16 + q * 4;
        f32x4 a4 = *(const f32x4*)&prm[576 + o0];
        f32x4 s4 = *(const f32x4*)&prm[672 + o0];
        #pragma unroll
        for (int nc = 0; nc < 2; ++nc) {
            int srow = wn * 32 + nc * 16 + sl, sgl = hw0 + srow;
            ushort4 pk;
            float r0 = acc2[m][nc][0] * a4[0] + s4[0] + Xres[((size_t)b * Cn + o0 + 0) * HWn + sgl];
            float r1 = acc2[m][nc][1] * a4[1] + s4[1] + Xres[((size_t)b * Cn + o0 + 1) * HWn + sgl];
            float r2 = acc2[m][nc][2] * a4[2] + s4[2] + Xres[((size_t)b * Cn + o0 + 2) * HWn + sgl];
            float r3 = acc2[m][nc][3] * a4[3] + s4[3] + Xres[((size_t)b * Cn + o0 + 3) * HWn + sgl];
            pk.x = f2bf(r0); pk.y = f2bf(r1); pk.z = f2bf(r2); pk.w = f2bf(r3);
            *(ushort4*)&Xs[srow * 200 + o0] = pk;
        }
    }
    __syncthreads();
    for (int v = t; v < 768; v += 256) {
        int s = v / 12, g = v % 12;
        *(u16x8*)&rbuf[((size_t)b * HWn + hw0 + s) * Cn + g * 8] = *(const u16x8*)&Xs[s * 200 + g * 8];
    }
}

// ---------------- FFN (chunked, LDS-slab-reused): out = Wf2 gelu(Wf1 r + bf1) + bf2 ----------------
// mid computed in 4 chunks of 96 channels; Rs staging slab is DEAD after the
// register hoist, so it doubles as the odd-chunk mid buffer. 26.6 KB LDS total.
// Barrier proof: stage->bar->hoist(reads Rs); chunk1's writes to Rs-area occur
// after chunk0's barrier, which post-dates all hoist reads. 1 barrier/chunk.
__global__ __launch_bounds__(256) void ffn_kernel(
    const ushort* __restrict__ rbuf,
    const ushort* __restrict__ wf1p, const float* __restrict__ bf1,
    const ushort* __restrict__ wf2p, const float* __restrict__ bf2,
    float* __restrict__ Out)
{
    __shared__ __align__(16) ushort S[2 * 6656];    // 26.6 KB: slab0 | slab1(=Rs)
    ushort* slab0 = S;
    ushort* Rs    = S + 6656;                       // staging + odd-chunk mid
    int bid = blockIdx.x, b = bid / TPI, hw0 = (bid % TPI) * NT;
    int t = threadIdx.x, lane = t & 63, wave = t >> 6;
    int wm = wave >> 1, wn = wave & 1, q = lane >> 4, sl = lane & 15;

    for (int v = t; v < 768; v += 256) {
        int s = v / 12, g = v % 12;
        *(u16x8*)&Rs[s * 104 + g * 8] = *(const u16x8*)&rbuf[((size_t)b * HWn + hw0 + s) * Cn + g * 8];
    }
    __syncthreads();

    // hoist r B-frags to registers (reused by all 4 chunks); Rs dead after this
    bf16x8 rb[3][2];
    #pragma unroll
    for (int kc = 0; kc < 3; ++kc) {
        rb[kc][0] = *(const bf16x8*)&Rs[(wn * 32 + sl) * 104 + kc * 32 + q * 8];
        rb[kc][1] = *(const bf16x8*)&Rs[(wn * 32 + 16 + sl) * 104 + kc * 32 + q * 8];
    }

    f32x4 acc2[3][2] = {};
    for (int c = 0; c < 4; ++c) {
        // ffn1 slice: global mt = c*6 + wm*3 + m, K=96 (3 kc)
        f32x4 a1[3][2] = {};
        #pragma unroll
        for (int kc = 0; kc < 3; ++kc)
            #pragma unroll
            for (int m = 0; m < 3; ++m) {
                bf16x8 af = *(const bf16x8*)&wf1p[(((c * 6 + wm * 3 + m) * 3 + kc) * 64 + lane) * 8];
                a1[m][0] = MFMA16(af, rb[kc][0], a1[m][0]);
                a1[m][1] = MFMA16(af, rb[kc][1], a1[m][1]);
            }
        // epilogue: gelu -> chunk slab
        ushort* mc = (c & 1) ? Rs : slab0;
        #pragma unroll
        for (int m = 0; m < 3; ++m) {
            int ol = (wm * 3 + m) * 16 + q * 4;          // 0..95 within chunk
            f32x4 b4 = *(const f32x4*)&bf1[c * 96 + ol];
            #pragma unroll
            for (int nc = 0; nc < 2; ++nc) {
                int srow = wn * 32 + nc * 16 + sl;
                ushort4 pk;
                pk.x = f2bf(gelu_f(a1[m][nc][0] + b4[0]));
                pk.y = f2bf(gelu_f(a1[m][nc][1] + b4[1]));
                pk.z = f2bf(gelu_f(a1[m][nc][2] + b4[2]));
                pk.w = f2bf(gelu_f(a1[m][nc][3] + b4[3]));
                *(ushort4*)&mc[srow * 104 + ol] = pk;
            }
        }
        __syncthreads();
        // ffn2 partial accumulation over this chunk (global kc = c*3 + kc)
        #pragma unroll
        for (int kc = 0; kc < 3; ++kc) {
            bf16x8 m0 = *(const bf16x8*)&mc[(wn * 32 + sl) * 104 + kc * 32 + q * 8];
            bf16x8 m1 = *(const bf16x8*)&mc[(wn * 32 + 16 + sl) * 104 + kc * 32 + q * 8];
            #pragma unroll
            for (int m = 0; m < 3; ++m) {
                bf16x8 af = *(const bf16x8*)&wf2p[(((wm * 3 + m) * 12 + c * 3 + kc) * 64 + lane) * 8];
                acc2[m][0] = MFMA16(af, m0, acc2[m][0]);
                acc2[m][1] = MFMA16(af, m1, acc2[m][1]);
            }
        }
        // no trailing barrier: next chunk writes the OTHER slab; its barrier
        // orders those writes against this chunk's reads (double-buffer).
    }
    #pragma unroll
    for (int m = 0; m < 3; ++m) {
        int o0 = (wm * 3 + m) * 16 + q * 4;
        f32x4 b4 = *(const f32x4*)&bf2[o0];
        #pragma unroll
        for (int nc = 0; nc < 2; ++nc) {
            int sgl = hw0 + wn * 32 + nc * 16 + sl;
            Out[((size_t)b * Cn + o0 + 0) * HWn + sgl] = acc2[m][nc][0] + b4[0];
            Out[((size_t)b * Cn + o0 + 1) * HWn + sgl] = acc2[m][nc][1] + b4[1];
            Out[((size_t)b * Cn + o0 + 2) * HWn + sgl] = acc2[m][nc][2] + b4[2];
            Out[((size_t)b * Cn + o0 + 3) * HWn + sgl] = acc2[m][nc][3] + b4[3];
        }
    }
}

extern "C" void kernel_launch(void* const* d_in, const int* in_sizes, int n_in,
                              void* d_out, int out_size, void* d_ws, size_t ws_size,
                              hipStream_t stream) {
    (void)in_sizes; (void)n_in; (void)out_size; (void)ws_size;
    const float* x   = (const float*)d_in[0];
    const float* w1  = (const float*)d_in[1];
    const float* b1  = (const float*)d_in[2];
    const float* g1  = (const float*)d_in[3];
    const float* be1 = (const float*)d_in[4];
    const float* m1  = (const float*)d_in[5];
    const float* v1  = (const float*)d_in[6];
    const float* wg  = (const float*)d_in[7];
    const float* bg  = (const float*)d_in[8];
    const float* gg  = (const float*)d_in[9];
    const float* beg = (const float*)d_in[10];
    const float* mg  = (const float*)d_in[11];
    const float* vg  = (const float*)d_in[12];
    const float* w2  = (const float*)d_in[13];
    const float* b2  = (const float*)d_in[14];
    const float* g2  = (const float*)d_in[15];
    const float* be2 = (const float*)d_in[16];
    const float* m2  = (const float*)d_in[17];
    const float* v2  = (const float*)d_in[18];
    const float* wf1 = (const float*)d_in[19];
    const float* bf1 = (const float*)d_in[20];
    const float* wf2 = (const float*)d_in[21];
    const float* bf2 = (const float*)d_in[22];
    float* out = (float*)d_out;

    char* base = (char*)d_ws;
    const size_t H_BYTES   = (size_t)Bn * HWn * Cn * 2;
    const size_t MIN_BYTES = (size_t)Bn * 112 * 2 * 96 * 4;
    ushort* hbuf  = (ushort*)base;
    float*  rmin2 = (float*)(base + H_BYTES);
    float*  cmin2 = (float*)(base + H_BYTES + MIN_BYTES);
    float*  prm   = (float*)(base + H_BYTES + 2 * MIN_BYTES);
    ushort* wpack = (ushort*)(base + H_BYTES + 2 * MIN_BYTES + 3072);
    ushort* w1p  = wpack;
    ushort* wgp  = wpack + 9216;
    ushort* w2p  = wpack + 46080;
    ushort* wf1p = wpack + 64512;
    ushort* wf2p = wpack + 101376;

    params_kernel<<<dim3(1), dim3(256), 0, stream>>>(
        b1, g1, be1, m1, v1, bg, gg, beg, mg, vg, b2, g2, be2, m2, v2, prm);
    pack_kernel<<<dim3(540), dim3(256), 0, stream>>>(w1, wg, w2, wf1, wf2, wpack);

    dim3 grid(Bn * TPI), blk(256);
    fc1_kernel<<<grid, blk, 0, stream>>>(x, w1p, prm, hbuf);
    mins_kernel<<<dim3(Bn * 2 * 112), blk, 0, stream>>>(hbuf, rmin2, cmin2);
    grapher_kernel<<<grid, blk, 0, stream>>>(hbuf, x, wgp, w2p, prm, cmin2, rmin2, hbuf);
    ffn_kernel<<<grid, blk, 0, stream>>>(hbuf, wf1p, bf1, wf2p, bf2, out);
}